// Round 9
// baseline (50.057 us; speedup 1.0000x reference)
//
#include <hip/hip_runtime.h>
#include <hip/hip_bf16.h>

typedef float f32x4 __attribute__((ext_vector_type(4)));
typedef __bf16 bf16x8 __attribute__((ext_vector_type(8)));

#define INF   8192             // in_features
#define FOLDS 127
#define LOCAL 128
#define OUTF  (FOLDS * LOCAL)  // 16256
#define BM    64               // batch rows per block
#define BN    64               // output features per block (half a fold)

// As/Bs: 64 rows x 128 cols bf16 (row stride 256B), XOR swizzle byte ^= (row&7)<<4
__device__ __forceinline__ void cvt_store8(char* lds, int byte, f32x4 v0, f32x4 v1) {
    bf16x8 w;
    w[0] = (__bf16)v0[0]; w[1] = (__bf16)v0[1]; w[2] = (__bf16)v0[2]; w[3] = (__bf16)v0[3];
    w[4] = (__bf16)v1[0]; w[5] = (__bf16)v1[1]; w[6] = (__bf16)v1[2]; w[7] = (__bf16)v1[3];
    *(bf16x8*)(lds + byte) = w;
}

__global__ __launch_bounds__(256, 5)   // 32 KB LDS -> 5 blocks/CU, 20 waves/CU
void local_linear_kernel(const float* __restrict__ x,
                         const float* __restrict__ W,
                         const float* __restrict__ bias,
                         float* __restrict__ out)
{
    __shared__ __align__(16) __bf16 As[BM * 128];   // x tile, 16 KiB
    __shared__ __align__(16) __bf16 Bs[BN * 128];   // W half-fold, 16 KiB

    const int mt = blockIdx.x;          // batch tile 0..31
    const int fn = blockIdx.y;          // fold-half 0..253
    const int f  = fn >> 1;             // fold 0..126
    const int bn0 = (fn & 1) * BN;      // 0 or 64 within the fold's 128 outputs
    const int t  = threadIdx.x;         // 0..255

    const int m0   = mt * BM;
    const int lane = t & 63;
    const int wid  = t >> 6;
    const int wf   = wid >> 1;   // 0..1: feature 32-block
    const int wb   = wid & 1;    // 0..1: batch 32-block
    const int r16  = lane & 15;
    const int kq   = lane >> 4;  // 0..3

    // ---- stage W half-fold -> Bs (fp32 -> bf16, swizzled): 64x128 ----
    const float* __restrict__ Wf = W + (size_t)f * (LOCAL * 128) + (size_t)bn0 * 128;
    #pragma unroll
    for (int it = 0; it < 4; ++it) {
        const int e   = it * 2048 + t * 8;
        const int row = e >> 7;        // l within half-fold (0..63)
        const int col = e & 127;       // k
        const float* g = Wf + row * 128 + col;
        f32x4 v0 = *(const f32x4*)g;
        f32x4 v1 = *(const f32x4*)(g + 4);
        cvt_store8((char*)Bs, (row * 256 + col * 2) ^ ((row & 7) << 4), v0, v1);
    }

    // ---- stage x tile -> As (fp32 -> bf16, swizzled): 64x128 ----
    const float* __restrict__ xg = x + (size_t)m0 * INF + (size_t)f * 64;
    #pragma unroll
    for (int it = 0; it < 4; ++it) {
        const int e   = it * 2048 + t * 8;
        const int row = e >> 7;        // batch row within tile (0..63)
        const int col = e & 127;       // k
        const float* g = xg + (size_t)row * INF + col;
        f32x4 v0 = *(const f32x4*)g;
        f32x4 v1 = *(const f32x4*)(g + 4);
        cvt_store8((char*)As, (row * 256 + col * 2) ^ ((row & 7) << 4), v0, v1);
    }
    __syncthreads();

    // ---- bias: varies along m (features) = reg dim -> one f32x4 per i ----
    // lane's 4 acc values (reg r) are features  i*16 + kq*4 + r
    f32x4 acc[2][2];
    #pragma unroll
    for (int i = 0; i < 2; ++i) {
        const f32x4 bv = *(const f32x4*)(bias + f * LOCAL + bn0 + wf * 32 + i * 16 + kq * 4);
        #pragma unroll
        for (int j = 0; j < 2; ++j)
            acc[i][j] = bv;
    }

    // ---- compute: A-operand = W (m = features), B-operand = x (n = batch) ----
    #pragma unroll
    for (int ks = 0; ks < 4; ++ks) {
        const int kof = ks * 32 + kq * 8;
        bf16x8 aw[2], bx[2];
        #pragma unroll
        for (int i = 0; i < 2; ++i) {
            const int row  = wf * 32 + i * 16 + r16;           // feature row in Bs
            const int byte = (row * 256 + kof * 2) ^ ((row & 7) << 4);
            aw[i] = *(const bf16x8*)((const char*)Bs + byte);
        }
        #pragma unroll
        for (int j = 0; j < 2; ++j) {
            const int row  = wb * 32 + j * 16 + r16;           // batch row in As
            const int byte = (row * 256 + kof * 2) ^ ((row & 7) << 4);
            bx[j] = *(const bf16x8*)((const char*)As + byte);
        }
        #pragma unroll
        for (int i = 0; i < 2; ++i)
            #pragma unroll
            for (int j = 0; j < 2; ++j)
                acc[i][j] = __builtin_amdgcn_mfma_f32_16x16x32_bf16(aw[i], bx[j], acc[i][j], 0, 0, 0);
    }

    // ---- epilogue: one dwordx4 store per acc tile ----
    // C/D map: n (batch within 16-group) = lane&15, m (feature) = kq*4 + r
    #pragma unroll
    for (int j = 0; j < 2; ++j) {
        const int brow = m0 + wb * 32 + j * 16 + r16;
        float* orow = out + (size_t)brow * OUTF + f * LOCAL + bn0 + wf * 32;
        #pragma unroll
        for (int i = 0; i < 2; ++i)
            *(f32x4*)(orow + i * 16 + kq * 4) = acc[i][j];
    }
}

extern "C" void kernel_launch(void* const* d_in, const int* in_sizes, int n_in,
                              void* d_out, int out_size, void* d_ws, size_t ws_size,
                              hipStream_t stream) {
    const float* x    = (const float*)d_in[0];
    const float* W    = (const float*)d_in[1];
    const float* bias = (const float*)d_in[2];
    float* out        = (float*)d_out;

    dim3 grid(2048 / BM, FOLDS * 2);   // 32 x 254 = 8128 blocks
    dim3 block(256);
    local_linear_kernel<<<grid, block, 0, stream>>>(x, W, bias, out);
}